// Round 5
// baseline (14249.745 us; speedup 1.0000x reference)
//
#include <hip/hip_runtime.h>
#include <math.h>

#define B 16
#define S 512
#define L 2400
#define TD 64
#define ML 256
#define NL 6
#define STEPS 32
#define LN_EPS 1e-5f
#define INV_SQRT_L 0.020412414523193152f
#define G 64          // row-groups per batch in k_attn (8 rows/block, 2 per wave)
#define RPW 2

__device__ __forceinline__ float gelu_exact(float x) {
    return 0.5f * x * (1.0f + erff(x * 0.7071067811865476f));
}

// ---------------- text encoder (runs once) ----------------
__global__ __launch_bounds__(256) void k_te1(const float* __restrict__ tc, const float* __restrict__ w,
                                             const float* __restrict__ bias, float* __restrict__ out1) {
    int idx = blockIdx.x * 256 + threadIdx.x;
    int p = idx & 255, oc = (idx >> 8) & 63, b = idx >> 14;
    const float* in = tc + b * ML;
    const float* wr = w + oc * 7;
    float acc = bias[oc];
#pragma unroll
    for (int k = 0; k < 7; ++k) {
        int q = p + k - 3;
        if (q >= 0 && q < ML) acc += in[q] * wr[k];
    }
    out1[idx] = gelu_exact(acc);
}

__global__ __launch_bounds__(256) void k_te2(const float* __restrict__ in1, const float* __restrict__ w,
                                             const float* __restrict__ bias, float* __restrict__ out2) {
    int idx = blockIdx.x * 256 + threadIdx.x;
    int p = idx & 255, oc = (idx >> 8) & 127, b = idx >> 15;
    const float* ib = in1 + b * 64 * ML;
    const float* wb = w + oc * 64 * 5;
    float acc = bias[oc];
    for (int ic = 0; ic < 64; ++ic) {
        const float* ir = ib + ic * ML;
        const float* wr = wb + ic * 5;
#pragma unroll
        for (int k = 0; k < 5; ++k) {
            int q = p + k - 2;
            if (q >= 0 && q < ML) acc += ir[q] * wr[k];
        }
    }
    out2[idx] = gelu_exact(acc);
}

__global__ __launch_bounds__(256) void k_te3(const float* __restrict__ in2, const float* __restrict__ w,
                                             const float* __restrict__ bias, float* __restrict__ tcond) {
    int b = blockIdx.x >> 6, oc = blockIdx.x & 63;
    int p = threadIdx.x;
    const float* ib = in2 + b * 128 * ML;
    const float* wb = w + oc * 128 * 3;
    float acc = bias[oc];
    for (int ic = 0; ic < 128; ++ic) {
        const float* ir = ib + ic * ML;
        const float* wr = wb + ic * 3;
        float s = ir[p] * wr[1];
        if (p > 0)      s += ir[p - 1] * wr[0];
        if (p < ML - 1) s += ir[p + 1] * wr[2];
        acc += s;
    }
    float v = gelu_exact(acc);
    __shared__ float red[4];
    for (int off = 32; off; off >>= 1) v += __shfl_xor(v, off);
    if ((threadIdx.x & 63) == 0) red[threadIdx.x >> 6] = v;
    __syncthreads();
    if (threadIdx.x == 0)
        tcond[b * TD + oc] = (red[0] + red[1] + red[2] + red[3]) * (1.0f / (float)ML);
}

// u[row]=sum_l g[l]*lw[row,l], v[row]=sum_l be[l]*lw[row,l] (LN folded into GEMM). grid 3600x256.
__global__ __launch_bounds__(256) void k_uv(const float* __restrict__ lw, const float* __restrict__ g,
                                            const float* __restrict__ be,
                                            float* __restrict__ u, float* __restrict__ v) {
    int wv = threadIdx.x >> 6, lane = threadIdx.x & 63;
    int row = blockIdx.x * 4 + wv;
    int j = row / L;
    const float4* wr = (const float4*)(lw + (size_t)row * L);
    const float4* gr = (const float4*)(g + j * L);
    const float4* br = (const float4*)(be + j * L);
    float su = 0.f, sv = 0.f;
    for (int i = lane; i < L / 4; i += 64) {
        float4 w4 = wr[i], g4 = gr[i], b4 = br[i];
        su += w4.x * g4.x + w4.y * g4.y + w4.z * g4.z + w4.w * g4.w;
        sv += w4.x * b4.x + w4.y * b4.y + w4.z * b4.z + w4.w * b4.w;
    }
    for (int off = 32; off; off >>= 1) { su += __shfl_xor(su, off); sv += __shfl_xor(sv, off); }
    if (lane == 0) { u[row] = su; v[row] = sv; }
}

__global__ __launch_bounds__(256) void k_scalars(const float* __restrict__ tcond,
                                                 const float* __restrict__ bw, const float* __restrict__ bb,
                                                 const float* __restrict__ gw, const float* __restrict__ gb,
                                                 float* __restrict__ biasS, float* __restrict__ gainS,
                                                 float* __restrict__ seg0) {
    int t = blockIdx.x * 256 + threadIdx.x;
    if (t < NL * B) {
        int j = t >> 4, b = t & 15;
        float a = 0.f;
        for (int d = 0; d < TD; ++d) a += tcond[b * TD + d] * bw[j * TD + d];
        biasS[t] = a + bb[j];
    } else if (t < 2 * NL * B) {
        int u2 = t - NL * B;
        int j = u2 >> 4, b = u2 & 15;
        float a = 0.f;
        for (int d = 0; d < TD; ++d) a += tcond[b * TD + d] * gw[j * TD + d];
        gainS[u2] = 1.0f / (1.0f + expf(-(a + gb[j])));
    }
    for (int i = t; i < B * L; i += 64 * 256) seg0[i] = 0.0f;
}

// ---------------- fused dot + online-softmax + mix (single pass over slices) ----------------
// grid B*G = 1024 blocks x 256 thr (4 waves). Wave owns RPW=2 sequential rows; acc[2400] in VGPRs.
// Single rv buffer (no pairing -- R4 showed the paired variant regresses via register pressure).
__global__ __launch_bounds__(256) void k_attn(const float* __restrict__ slices,
                                              const float* __restrict__ seg,
                                              const int* __restrict__ mask,
                                              const float* __restrict__ biasS,
                                              float* __restrict__ part, float* __restrict__ hdr) {
    __shared__ float4 cbuf[4][600];   // 38.4 KB
    __shared__ float wred[8];
    int bid = blockIdx.x;
    int b = bid >> 6, grp = bid & 63;
    int wv = threadIdx.x >> 6, lane = threadIdx.x & 63;
    int t = threadIdx.x;

    // seg chunk in VGPRs (lane owns float4 indices lane, lane+64, ..., 600 total)
    float4 segv[10];
    const float4* segp = (const float4*)(seg + b * L);
#pragma unroll
    for (int w = 0; w < 10; ++w) {
        int i = w * 64 + lane;
        segv[w] = (i < 600) ? segp[i] : make_float4(0.f, 0.f, 0.f, 0.f);
    }
    float4 accv[10];
#pragma unroll
    for (int w = 0; w < 10; ++w) accv[w] = make_float4(0.f, 0.f, 0.f, 0.f);

    float m = -INFINITY, z = 0.f;
    float bscale = biasS[b];
    int s0 = grp * (S / G) + wv * RPW;
    for (int r = 0; r < RPW; ++r) {
        int s = s0 + r;
        const float4* rp = (const float4*)(slices + ((size_t)b * S + s) * L);
        float4 rv[10];
#pragma unroll
        for (int w = 0; w < 10; ++w) {
            int i = w * 64 + lane;
            rv[w] = (i < 600) ? rp[i] : make_float4(0.f, 0.f, 0.f, 0.f);
        }
        float d = 0.f;
#pragma unroll
        for (int w = 0; w < 10; ++w)
            d += rv[w].x * segv[w].x + rv[w].y * segv[w].y + rv[w].z * segv[w].z + rv[w].w * segv[w].w;
#pragma unroll
        for (int off = 32; off; off >>= 1) d += __shfl_xor(d, off);
        if (mask[b * S + s]) {
            float logit = d * INV_SQRT_L + bscale;
            float p;
            if (logit > m) {
                float f = expf(m - logit);   // m == -inf -> 0, well-defined
                z *= f;
#pragma unroll
                for (int w = 0; w < 10; ++w) {
                    accv[w].x *= f; accv[w].y *= f; accv[w].z *= f; accv[w].w *= f;
                }
                m = logit; p = 1.0f;
            } else {
                p = expf(logit - m);
            }
            z += p;
#pragma unroll
            for (int w = 0; w < 10; ++w) {
                accv[w].x += p * rv[w].x; accv[w].y += p * rv[w].y;
                accv[w].z += p * rv[w].z; accv[w].w += p * rv[w].w;
            }
        }
    }

    // cross-wave combine at block max M
    if (lane == 0) wred[wv] = m;
    __syncthreads();
    float M = fmaxf(fmaxf(wred[0], wred[1]), fmaxf(wred[2], wred[3]));
    float f = (m == -INFINITY) ? 0.f : expf(m - M);
    if (lane == 0) wred[4 + wv] = z * f;
#pragma unroll
    for (int w = 0; w < 10; ++w) {
        int i = w * 64 + lane;
        if (i < 600) {
            float4 a = accv[w];
            a.x *= f; a.y *= f; a.z *= f; a.w *= f;
            cbuf[wv][i] = a;
        }
    }
    __syncthreads();
    float Z = wred[4] + wred[5] + wred[6] + wred[7];
    float4* pp = (float4*)part;
    for (int i = t; i < 600; i += 256) {
        float4 c0 = cbuf[0][i], c1 = cbuf[1][i], c2 = cbuf[2][i], c3 = cbuf[3][i];
        float4 o;
        o.x = c0.x + c1.x + c2.x + c3.x;
        o.y = c0.y + c1.y + c2.y + c3.y;
        o.z = c0.z + c1.z + c2.z + c3.z;
        o.w = c0.w + c1.w + c2.w + c3.w;
        pp[(size_t)bid * 600 + i] = o;
    }
    if (t == 0) { hdr[2 * bid] = M; hdr[2 * bid + 1] = Z; }
}

// ---------------- combine partials + gain + conv9 + residual + LN stat partials ----------------
// grid B*10 = 160 blocks; each owns 240 cols (+-4 halo). Writes xg = x*ln_g (GEMM-ready).
__global__ __launch_bounds__(256) void k_comb(const float* __restrict__ part, const float* __restrict__ hdr,
                                              const float* __restrict__ gainS, const float* __restrict__ cw,
                                              const float* __restrict__ lng,
                                              const float* __restrict__ seg,
                                              float* __restrict__ xg, float* __restrict__ statsP) {
    __shared__ float sm[248];
    __shared__ float fld[G];
    __shared__ float red[9];
    int b = blockIdx.x / 10, ch = blockIdx.x % 10;
    int l0 = ch * 240;
    int t = threadIdx.x;

    if (t < 64) {
        float mg = (t < G) ? hdr[2 * (b * G + t)] : -INFINITY;
#pragma unroll
        for (int off = 32; off; off >>= 1) mg = fmaxf(mg, __shfl_xor(mg, off));
        if (t == 0) red[8] = mg;
    }
    __syncthreads();
    float M = red[8];
    if (t < 64) {
        float fg = 0.f, zg = 0.f;
        if (t < G) {
            float mg = hdr[2 * (b * G + t)];
            fg = (mg == -INFINITY) ? 0.f : expf(mg - M);
            zg = fg * hdr[2 * (b * G + t) + 1];
            fld[t] = fg;
        }
#pragma unroll
        for (int off = 32; off; off >>= 1) zg += __shfl_xor(zg, off);
        if (t == 0) red[0] = zg;
    }
    __syncthreads();
    float Z = red[0];
    float ginv = gainS[b] / Z;

    float v = 0.f;
    int c = l0 - 4 + t;
    if (t < 248) {
        if (c >= 0 && c < L) {
            for (int g2 = 0; g2 < G; ++g2)
                v += fld[g2] * part[((size_t)(b * G + g2)) * L + c];
            v *= ginv;
        }
        sm[t] = v;
    }
    __syncthreads();

    float s1 = 0.f, s2 = 0.f;
    if (t < 240) {
        float x = 0.f;
#pragma unroll
        for (int k = 0; k < 9; ++k) x += sm[t + k] * cw[k];
        x += seg[b * L + l0 + t];
        xg[b * L + l0 + t] = x * lng[l0 + t];
        s1 = x; s2 = x * x;
    }
#pragma unroll
    for (int off = 32; off; off >>= 1) { s1 += __shfl_xor(s1, off); s2 += __shfl_xor(s2, off); }
    int wv = t >> 6;
    if ((t & 63) == 0) { red[wv] = s1; red[4 + wv] = s2; }
    __syncthreads();
    if (t == 0) {
        statsP[blockIdx.x * 2]     = red[0] + red[1] + red[2] + red[3];
        statsP[blockIdx.x * 2 + 1] = red[4] + red[5] + red[6] + red[7];
    }
}

// ---------------- LN (folded) + seg' = xn @ lw^T + lb ----------------
// grid 600 blocks x 4 rows; 256 thr = 4 row-groups x 64 lanes. Double-buffered LDS, 1 barrier/tile.
__global__ __launch_bounds__(256) void k_lin(const float* __restrict__ xg, const float* __restrict__ statsP,
                                             const float* __restrict__ lw, const float* __restrict__ lb,
                                             const float* __restrict__ u, const float* __restrict__ v,
                                             float* __restrict__ segn, float* __restrict__ outp, int step) {
    __shared__ float4 sxg[2][B][64];   // 32 KB double-buffered tile of x*g
    __shared__ float smu[B], srr[B];
    int t = threadIdx.x;
    if (t < B) {
        float s1 = 0.f, s2 = 0.f;
#pragma unroll
        for (int k = 0; k < 10; ++k) {
            s1 += statsP[(t * 10 + k) * 2];
            s2 += statsP[(t * 10 + k) * 2 + 1];
        }
        float mu = s1 * (1.0f / (float)L);
        float var = s2 * (1.0f / (float)L) - mu * mu;
        smu[t] = mu;
        srr[t] = 1.0f / sqrtf(var + LN_EPS);
    }
    int rg = t >> 6, lane = t & 63;
    int lp = blockIdx.x * 4 + rg;
    float acc[B];
#pragma unroll
    for (int i = 0; i < B; ++i) acc[i] = 0.f;
    const float4* lwr = (const float4*)(lw + (size_t)lp * L);
    const float4* xg4 = (const float4*)xg;

    float4 pf[4];
#pragma unroll
    for (int q = 0; q < 4; ++q) {
        int i = t + q * 256;
        pf[q] = xg4[(i >> 6) * 600 + (i & 63)];
    }
#pragma unroll
    for (int q = 0; q < 4; ++q) {
        int i = t + q * 256;
        sxg[0][i >> 6][i & 63] = pf[q];
    }
    __syncthreads();

    for (int tile = 0; tile < 10; ++tile) {
        if (tile < 9) {
#pragma unroll
            for (int q = 0; q < 4; ++q) {
                int i = t + q * 256;
                int gi = (tile + 1) * 64 + (i & 63);
                pf[q] = (gi < 600) ? xg4[(i >> 6) * 600 + gi] : make_float4(0.f, 0.f, 0.f, 0.f);
            }
        }
        int colbase = tile * 256 + lane * 4;
        if (colbase < L) {
            float4 w4 = lwr[tile * 64 + lane];
#pragma unroll
            for (int bb = 0; bb < B; ++bb) {
                float4 xv = sxg[tile & 1][bb][lane];
                acc[bb] += xv.x * w4.x + xv.y * w4.y + xv.z * w4.z + xv.w * w4.w;
            }
        }
        if (tile < 9) {
#pragma unroll
            for (int q = 0; q < 4; ++q) {
                int i = t + q * 256;
                sxg[(tile + 1) & 1][i >> 6][i & 63] = pf[q];
            }
        }
        __syncthreads();
    }
#pragma unroll
    for (int off = 32; off; off >>= 1) {
#pragma unroll
        for (int bb = 0; bb < B; ++bb) acc[bb] += __shfl_xor(acc[bb], off);
    }
    if (lane == 0) {
        float ur = u[lp];
        float vr = v[lp] + lb[lp];
#pragma unroll
        for (int bb = 0; bb < B; ++bb) {
            float a = srr[bb] * (acc[bb] - smu[bb] * ur) + vr;
            segn[bb * L + lp] = a;
            if (outp) outp[bb * (STEPS * L) + step * L + lp] = a;
        }
    }
}

extern "C" void kernel_launch(void* const* d_in, const int* in_sizes, int n_in,
                              void* d_out, int out_size, void* d_ws, size_t ws_size,
                              hipStream_t stream) {
    const float* slices  = (const float*)d_in[0];
    const float* text    = (const float*)d_in[1];
    const float* tc1_w   = (const float*)d_in[2];
    const float* tc1_b   = (const float*)d_in[3];
    const float* tc2_w   = (const float*)d_in[4];
    const float* tc2_b   = (const float*)d_in[5];
    const float* tc3_w   = (const float*)d_in[6];
    const float* tc3_b   = (const float*)d_in[7];
    const float* lin_w   = (const float*)d_in[8];
    const float* lin_b   = (const float*)d_in[9];
    const float* dconv_w = (const float*)d_in[10];
    const float* bias_w  = (const float*)d_in[11];
    const float* bias_b  = (const float*)d_in[12];
    const float* gain_w  = (const float*)d_in[13];
    const float* gain_b  = (const float*)d_in[14];
    const float* ln_g    = (const float*)d_in[15];
    const float* ln_be   = (const float*)d_in[16];
    const int*   mask    = (const int*)d_in[17];
    float* out = (float*)d_out;

    float* W0    = (float*)d_ws;
    float* tcond = W0;                  // 1024
    float* A     = W0 + 1024;
    // setup-only (dead after k_te3):
    float* te1   = A;                   // 262144
    float* te2   = A + 262144;          // 524288
    // loop buffers (part overlays te1/te2):
    float* part  = A;                   // B*G*L = 2,457,600
    float* hdr   = A + 2457600;         // 2*B*G = 2048
    float* biasS = hdr + 2048;          // 96
    float* gainS = biasS + 96;          // 96
    float* xg    = gainS + 96;          // 38400
    float* statsP= xg + 38400;          // 320
    float* segA  = statsP + 320;        // 38400
    float* segB  = segA + 38400;        // 38400
    float* U     = segB + 38400;        // 14400
    float* V     = U + 14400;           // 14400

    k_te1<<<1024, 256, 0, stream>>>(text, tc1_w, tc1_b, te1);
    k_te2<<<2048, 256, 0, stream>>>(te1, tc2_w, tc2_b, te2);
    k_te3<<<1024, 256, 0, stream>>>(te2, tc3_w, tc3_b, tcond);
    k_uv <<<3600, 256, 0, stream>>>(lin_w, ln_g, ln_be, U, V);
    k_scalars<<<64, 256, 0, stream>>>(tcond, bias_w, bias_b, gain_w, gain_b, biasS, gainS, segA);

    float* segc = segA;
    float* segn = segB;
    for (int step = 0; step < STEPS; ++step) {
        for (int j = 0; j < NL; ++j) {
            k_attn<<<B * G, 256, 0, stream>>>(slices, segc, mask, biasS + j * B, part, hdr);
            k_comb<<<B * 10, 256, 0, stream>>>(part, hdr, gainS + j * B, dconv_w + j * 9,
                                               ln_g + j * L, segc, xg, statsP);
            k_lin<<<600, 256, 0, stream>>>(xg, statsP, lin_w + (size_t)j * L * L,
                                           lin_b + j * L, U + j * L, V + j * L, segn,
                                           (j == NL - 1) ? out : nullptr, step);
            float* tmp = segc; segc = segn; segn = tmp;
        }
    }
}

// Round 6
// 9104.341 us; speedup vs baseline: 1.5652x; 1.5652x over previous
//
#include <hip/hip_runtime.h>
#include <math.h>

#define B 16
#define S 512
#define L 2400
#define TD 64
#define ML 256
#define NL 6
#define STEPS 32
#define LN_EPS 1e-5f
#define INV_SQRT_L 0.020412414523193152f
#define G 32          // row-groups per batch in k_attn
#define RPW 4         // rows per wave (S / G / 4 waves)

__device__ __forceinline__ float gelu_exact(float x) {
    return 0.5f * x * (1.0f + erff(x * 0.7071067811865476f));
}

// ---------------- text encoder (runs once) ----------------
__global__ __launch_bounds__(256) void k_te1(const float* __restrict__ tc, const float* __restrict__ w,
                                             const float* __restrict__ bias, float* __restrict__ out1) {
    int idx = blockIdx.x * 256 + threadIdx.x;
    int p = idx & 255, oc = (idx >> 8) & 63, b = idx >> 14;
    const float* in = tc + b * ML;
    const float* wr = w + oc * 7;
    float acc = bias[oc];
#pragma unroll
    for (int k = 0; k < 7; ++k) {
        int q = p + k - 3;
        if (q >= 0 && q < ML) acc += in[q] * wr[k];
    }
    out1[idx] = gelu_exact(acc);
}

__global__ __launch_bounds__(256) void k_te2(const float* __restrict__ in1, const float* __restrict__ w,
                                             const float* __restrict__ bias, float* __restrict__ out2) {
    int idx = blockIdx.x * 256 + threadIdx.x;
    int p = idx & 255, oc = (idx >> 8) & 127, b = idx >> 15;
    const float* ib = in1 + b * 64 * ML;
    const float* wb = w + oc * 64 * 5;
    float acc = bias[oc];
    for (int ic = 0; ic < 64; ++ic) {
        const float* ir = ib + ic * ML;
        const float* wr = wb + ic * 5;
#pragma unroll
        for (int k = 0; k < 5; ++k) {
            int q = p + k - 2;
            if (q >= 0 && q < ML) acc += ir[q] * wr[k];
        }
    }
    out2[idx] = gelu_exact(acc);
}

__global__ __launch_bounds__(256) void k_te3(const float* __restrict__ in2, const float* __restrict__ w,
                                             const float* __restrict__ bias, float* __restrict__ tcond) {
    int b = blockIdx.x >> 6, oc = blockIdx.x & 63;
    int p = threadIdx.x;
    const float* ib = in2 + b * 128 * ML;
    const float* wb = w + oc * 128 * 3;
    float acc = bias[oc];
    for (int ic = 0; ic < 128; ++ic) {
        const float* ir = ib + ic * ML;
        const float* wr = wb + ic * 3;
        float s = ir[p] * wr[1];
        if (p > 0)      s += ir[p - 1] * wr[0];
        if (p < ML - 1) s += ir[p + 1] * wr[2];
        acc += s;
    }
    float v = gelu_exact(acc);
    __shared__ float red[4];
    for (int off = 32; off; off >>= 1) v += __shfl_xor(v, off);
    if ((threadIdx.x & 63) == 0) red[threadIdx.x >> 6] = v;
    __syncthreads();
    if (threadIdx.x == 0)
        tcond[b * TD + oc] = (red[0] + red[1] + red[2] + red[3]) * (1.0f / (float)ML);
}

// u[row]=sum_l g[l]*lw[row,l], v[row]=sum_l be[l]*lw[row,l] (LN folded into GEMM). grid 3600x256.
__global__ __launch_bounds__(256) void k_uv(const float* __restrict__ lw, const float* __restrict__ g,
                                            const float* __restrict__ be,
                                            float* __restrict__ u, float* __restrict__ v) {
    int wv = threadIdx.x >> 6, lane = threadIdx.x & 63;
    int row = blockIdx.x * 4 + wv;
    int j = row / L;
    const float4* wr = (const float4*)(lw + (size_t)row * L);
    const float4* gr = (const float4*)(g + j * L);
    const float4* br = (const float4*)(be + j * L);
    float su = 0.f, sv = 0.f;
    for (int i = lane; i < L / 4; i += 64) {
        float4 w4 = wr[i], g4 = gr[i], b4 = br[i];
        su += w4.x * g4.x + w4.y * g4.y + w4.z * g4.z + w4.w * g4.w;
        sv += w4.x * b4.x + w4.y * b4.y + w4.z * b4.z + w4.w * b4.w;
    }
    for (int off = 32; off; off >>= 1) { su += __shfl_xor(su, off); sv += __shfl_xor(sv, off); }
    if (lane == 0) { u[row] = su; v[row] = sv; }
}

__global__ __launch_bounds__(256) void k_scalars(const float* __restrict__ tcond,
                                                 const float* __restrict__ bw, const float* __restrict__ bb,
                                                 const float* __restrict__ gw, const float* __restrict__ gb,
                                                 float* __restrict__ biasS, float* __restrict__ gainS,
                                                 float* __restrict__ seg0) {
    int t = blockIdx.x * 256 + threadIdx.x;
    if (t < NL * B) {
        int j = t >> 4, b = t & 15;
        float a = 0.f;
        for (int d = 0; d < TD; ++d) a += tcond[b * TD + d] * bw[j * TD + d];
        biasS[t] = a + bb[j];
    } else if (t < 2 * NL * B) {
        int u2 = t - NL * B;
        int j = u2 >> 4, b = u2 & 15;
        float a = 0.f;
        for (int d = 0; d < TD; ++d) a += tcond[b * TD + d] * gw[j * TD + d];
        gainS[u2] = 1.0f / (1.0f + expf(-(a + gb[j])));
    }
    for (int i = t; i < B * L; i += 64 * 256) seg0[i] = 0.0f;
}

// ---------------- fused dot + online-softmax + mix (single pass over slices) ----------------
// grid B*G = 512 blocks x 256 thr (4 waves). Wave owns RPW=4 rows; acc[2400] in VGPRs.
// Emits per-block partial (M, Z, acc[2400] referenced to M).
__global__ __launch_bounds__(256) void k_attn(const float* __restrict__ slices,
                                              const float* __restrict__ seg,
                                              const int* __restrict__ mask,
                                              const float* __restrict__ biasS,
                                              float* __restrict__ part, float* __restrict__ hdr,
                                              float* __restrict__ stats) {
    __shared__ float4 cbuf[4][600];   // 38.4 KB, used only at combine
    __shared__ float wred[8];
    int bid = blockIdx.x;
    int b = bid >> 5, grp = bid & 31;
    int wv = threadIdx.x >> 6, lane = threadIdx.x & 63;

    // seg chunk in VGPRs (lane owns float4 indices lane, lane+64, ..., 600 total)
    float4 segv[10];
    const float4* segp = (const float4*)(seg + b * L);
#pragma unroll
    for (int w = 0; w < 10; ++w) {
        int i = w * 64 + lane;
        segv[w] = (i < 600) ? segp[i] : make_float4(0.f, 0.f, 0.f, 0.f);
    }
    float4 accv[10];
#pragma unroll
    for (int w = 0; w < 10; ++w) accv[w] = make_float4(0.f, 0.f, 0.f, 0.f);

    float m = -INFINITY, z = 0.f;
    float bscale = biasS[b];
    int s0 = grp * (S / G) + wv * RPW;
    for (int r = 0; r < RPW; ++r) {
        int s = s0 + r;
        const float4* rp = (const float4*)(slices + ((size_t)b * S + s) * L);
        float4 rv[10];
#pragma unroll
        for (int w = 0; w < 10; ++w) {
            int i = w * 64 + lane;
            rv[w] = (i < 600) ? rp[i] : make_float4(0.f, 0.f, 0.f, 0.f);
        }
        float d = 0.f;
#pragma unroll
        for (int w = 0; w < 10; ++w)
            d += rv[w].x * segv[w].x + rv[w].y * segv[w].y + rv[w].z * segv[w].z + rv[w].w * segv[w].w;
#pragma unroll
        for (int off = 32; off; off >>= 1) d += __shfl_xor(d, off);
        if (mask[b * S + s]) {
            float logit = d * INV_SQRT_L + bscale;
            float p;
            if (logit > m) {
                float f = expf(m - logit);   // m == -inf -> 0, well-defined
                z *= f;
#pragma unroll
                for (int w = 0; w < 10; ++w) {
                    accv[w].x *= f; accv[w].y *= f; accv[w].z *= f; accv[w].w *= f;
                }
                m = logit; p = 1.0f;
            } else {
                p = expf(logit - m);
            }
            z += p;
#pragma unroll
            for (int w = 0; w < 10; ++w) {
                accv[w].x += p * rv[w].x; accv[w].y += p * rv[w].y;
                accv[w].z += p * rv[w].z; accv[w].w += p * rv[w].w;
            }
        }
    }

    // cross-wave combine at block max M
    if (lane == 0) wred[wv] = m;
    __syncthreads();
    float M = fmaxf(fmaxf(wred[0], wred[1]), fmaxf(wred[2], wred[3]));
    float f = (m == -INFINITY) ? 0.f : expf(m - M);
    if (lane == 0) wred[4 + wv] = z * f;
#pragma unroll
    for (int w = 0; w < 10; ++w) {
        int i = w * 64 + lane;
        if (i < 600) {
            float4 a = accv[w];
            a.x *= f; a.y *= f; a.z *= f; a.w *= f;
            cbuf[wv][i] = a;
        }
    }
    __syncthreads();
    float Z = wred[4] + wred[5] + wred[6] + wred[7];
    float4* pp = (float4*)part;
    for (int i = threadIdx.x; i < 600; i += 256) {
        float4 c0 = cbuf[0][i], c1 = cbuf[1][i], c2 = cbuf[2][i], c3 = cbuf[3][i];
        float4 o;
        o.x = c0.x + c1.x + c2.x + c3.x;
        o.y = c0.y + c1.y + c2.y + c3.y;
        o.z = c0.z + c1.z + c2.z + c3.z;
        o.w = c0.w + c1.w + c2.w + c3.w;
        pp[(size_t)bid * 600 + i] = o;
    }
    if (threadIdx.x == 0) { hdr[2 * bid] = M; hdr[2 * bid + 1] = Z; }
    if (bid == 0 && threadIdx.x < 2 * B) stats[threadIdx.x] = 0.f;  // zero LN stats for this layer-step
}

// ---------------- combine partials + gain + conv9 + residual + LN stats ----------------
// grid B*10 = 160 blocks; each owns 240 cols (+-4 halo).
__global__ __launch_bounds__(256) void k_comb(const float* __restrict__ part, const float* __restrict__ hdr,
                                              const float* __restrict__ gainS, const float* __restrict__ cw,
                                              const float* __restrict__ seg,
                                              float* __restrict__ xbuf, float* __restrict__ stats) {
    __shared__ float sm[248];
    __shared__ float fld[G];
    __shared__ float red[9];
    int b = blockIdx.x / 10, ch = blockIdx.x % 10;
    int l0 = ch * 240;
    int t = threadIdx.x;

    // per-b global max M over G group headers (wave 0)
    if (t < 64) {
        float mg = (t < G) ? hdr[2 * (b * G + t)] : -INFINITY;
#pragma unroll
        for (int off = 32; off; off >>= 1) mg = fmaxf(mg, __shfl_xor(mg, off));
        if (t == 0) red[8] = mg;
    }
    __syncthreads();
    float M = red[8];
    if (t < 64) {
        float fg = 0.f, zg = 0.f;
        if (t < G) {
            float mg = hdr[2 * (b * G + t)];
            fg = (mg == -INFINITY) ? 0.f : expf(mg - M);
            zg = fg * hdr[2 * (b * G + t) + 1];
            fld[t] = fg;
        }
#pragma unroll
        for (int off = 32; off; off >>= 1) zg += __shfl_xor(zg, off);
        if (t == 0) red[0] = zg;
    }
    __syncthreads();
    float Z = red[0];
    float ginv = gainS[b] / Z;

    // combined mixed for cols [l0-4, l0+244)
    float v = 0.f;
    int c = l0 - 4 + t;
    if (t < 248) {
        if (c >= 0 && c < L) {
            for (int g2 = 0; g2 < G; ++g2)
                v += fld[g2] * part[((size_t)(b * G + g2)) * L + c];
            v *= ginv;
        }
        sm[t] = v;
    }
    __syncthreads();

    float s1 = 0.f, s2 = 0.f;
    if (t < 240) {
        float x = 0.f;
#pragma unroll
        for (int k = 0; k < 9; ++k) x += sm[t + k] * cw[k];
        x += seg[b * L + l0 + t];
        xbuf[b * L + l0 + t] = x;
        s1 = x; s2 = x * x;
    }
#pragma unroll
    for (int off = 32; off; off >>= 1) { s1 += __shfl_xor(s1, off); s2 += __shfl_xor(s2, off); }
    int wv = t >> 6;
    if ((t & 63) == 0) { red[wv] = s1; red[4 + wv] = s2; }
    __syncthreads();
    if (t == 0) {
        atomicAdd(&stats[2 * b], red[0] + red[1] + red[2] + red[3]);
        atomicAdd(&stats[2 * b + 1], red[4] + red[5] + red[6] + red[7]);
    }
}

// ---------------- LN (folded) + seg' = xn @ lw^T + lb ----------------
// grid 600 blocks x 4 rows; 256 thr = 4 row-groups x 64 lanes.
__global__ __launch_bounds__(256) void k_lin(const float* __restrict__ xbuf, const float* __restrict__ stats,
                                             const float* __restrict__ g, const float* __restrict__ lw,
                                             const float* __restrict__ lb,
                                             const float* __restrict__ u, const float* __restrict__ v,
                                             float* __restrict__ segn, float* __restrict__ outp, int step) {
    __shared__ float4 sxg[B][64];   // 16 KB tile of x*g
    __shared__ float smu[B], srr[B];
    int t = threadIdx.x;
    if (t < B) {
        float s1 = stats[2 * t], s2 = stats[2 * t + 1];
        float mu = s1 * (1.0f / (float)L);
        float var = s2 * (1.0f / (float)L) - mu * mu;
        smu[t] = mu;
        srr[t] = 1.0f / sqrtf(var + LN_EPS);
    }
    int rg = t >> 6, lane = t & 63;
    int lp = blockIdx.x * 4 + rg;
    float acc[B];
#pragma unroll
    for (int i = 0; i < B; ++i) acc[i] = 0.f;
    const float4* lwr = (const float4*)(lw + (size_t)lp * L);
    const float4* g4p = (const float4*)g;
    for (int tile = 0; tile < 10; ++tile) {
        int lt = tile * 256;
        __syncthreads();
        for (int i = t; i < B * 64; i += 256) {
            int bb = i >> 6, c4 = i & 63;
            float4 xv = make_float4(0.f, 0.f, 0.f, 0.f);
            if (lt + c4 * 4 < L) {
                int gi = (lt >> 2) + c4;
                xv = ((const float4*)(xbuf + bb * L))[gi];
                float4 gv = g4p[gi];
                xv.x *= gv.x; xv.y *= gv.y; xv.z *= gv.z; xv.w *= gv.w;
            }
            sxg[bb][c4] = xv;
        }
        __syncthreads();
        int colbase = lt + lane * 4;
        if (colbase < L) {
            float4 w4 = lwr[(lt >> 2) + lane];
#pragma unroll
            for (int bb = 0; bb < B; ++bb) {
                float4 xv = sxg[bb][lane];
                acc[bb] += xv.x * w4.x + xv.y * w4.y + xv.z * w4.z + xv.w * w4.w;
            }
        }
    }
#pragma unroll
    for (int off = 32; off; off >>= 1) {
#pragma unroll
        for (int bb = 0; bb < B; ++bb) acc[bb] += __shfl_xor(acc[bb], off);
    }
    if (lane == 0) {
        float ur = u[lp];
        float vr = v[lp] + lb[lp];
#pragma unroll
        for (int bb = 0; bb < B; ++bb) {
            float a = srr[bb] * (acc[bb] - smu[bb] * ur) + vr;
            segn[bb * L + lp] = a;
            if (outp) outp[bb * (STEPS * L) + step * L + lp] = a;
        }
    }
}

extern "C" void kernel_launch(void* const* d_in, const int* in_sizes, int n_in,
                              void* d_out, int out_size, void* d_ws, size_t ws_size,
                              hipStream_t stream) {
    const float* slices  = (const float*)d_in[0];
    const float* text    = (const float*)d_in[1];
    const float* tc1_w   = (const float*)d_in[2];
    const float* tc1_b   = (const float*)d_in[3];
    const float* tc2_w   = (const float*)d_in[4];
    const float* tc2_b   = (const float*)d_in[5];
    const float* tc3_w   = (const float*)d_in[6];
    const float* tc3_b   = (const float*)d_in[7];
    const float* lin_w   = (const float*)d_in[8];
    const float* lin_b   = (const float*)d_in[9];
    const float* dconv_w = (const float*)d_in[10];
    const float* bias_w  = (const float*)d_in[11];
    const float* bias_b  = (const float*)d_in[12];
    const float* gain_w  = (const float*)d_in[13];
    const float* gain_b  = (const float*)d_in[14];
    const float* ln_g    = (const float*)d_in[15];
    const float* ln_be   = (const float*)d_in[16];
    const int*   mask    = (const int*)d_in[17];
    float* out = (float*)d_out;

    float* W0    = (float*)d_ws;
    // region A: te1/te2 (setup only) overlapped with attn partials (loop only)
    float* A     = W0 + 1024;
    float* tcond = W0;                  // 1024
    float* te1   = A;                   // 262144 (setup)
    float* te2   = A + 262144;          // 524288 (setup)
    float* part  = A;                   // B*G*L = 1,228,800 (loop)
    float* hdr   = A + 1228800;         // 2*B*G = 1024
    float* biasS = A + 1229824;         // 96
    float* gainS = biasS + 96;          // 96
    float* xbuf  = gainS + 96;          // 38400
    float* stats = xbuf + 38400;        // 32
    float* segA  = stats + 32;          // 38400
    float* segB  = segA + 38400;        // 38400
    float* U     = segB + 38400;        // 14400
    float* V     = U + 14400;           // 14400

    k_te1<<<1024, 256, 0, stream>>>(text, tc1_w, tc1_b, te1);
    k_te2<<<2048, 256, 0, stream>>>(te1, tc2_w, tc2_b, te2);
    k_te3<<<1024, 256, 0, stream>>>(te2, tc3_w, tc3_b, tcond);
    k_uv <<<3600, 256, 0, stream>>>(lin_w, ln_g, ln_be, U, V);
    k_scalars<<<64, 256, 0, stream>>>(tcond, bias_w, bias_b, gain_w, gain_b, biasS, gainS, segA);

    float* segc = segA;
    float* segn = segB;
    for (int step = 0; step < STEPS; ++step) {
        for (int j = 0; j < NL; ++j) {
            k_attn<<<B * G, 256, 0, stream>>>(slices, segc, mask, biasS + j * B, part, hdr, stats);
            k_comb<<<B * 10, 256, 0, stream>>>(part, hdr, gainS + j * B, dconv_w + j * 9,
                                               segc, xbuf, stats);
            k_lin<<<600, 256, 0, stream>>>(xbuf, stats, ln_g + j * L, lin_w + (size_t)j * L * L,
                                           lin_b + j * L, U + j * L, V + j * L, segn,
                                           (j == NL - 1) ? out : nullptr, step);
            float* tmp = segc; segc = segn; segn = tmp;
        }
    }
}